// Round 2
// baseline (1055.039 us; speedup 1.0000x reference)
//
#include <hip/hip_runtime.h>
#include <math.h>

typedef __attribute__((ext_vector_type(8))) short  bf16x8;
typedef __attribute__((ext_vector_type(4))) float  f32x4;
typedef __attribute__((ext_vector_type(8))) unsigned short u16x8;

#define HID 128
#define BM  32      // edges per tile
#define TPB 4       // tiles per block (sequential)

__device__ __forceinline__ unsigned short f2bf(float f) {
    union { float f; unsigned u; } v; v.f = f;
    unsigned u = v.u;
    return (unsigned short)((u + 0x7fffu + ((u >> 16) & 1u)) >> 16);
}
__device__ __forceinline__ float bf2f(unsigned short h) {
    union { unsigned u; float f; } v; v.u = ((unsigned)h) << 16;
    return v.f;
}
// tanh-form GELU: max |diff vs exact| ~3e-4, ~9 VALU ops (2 on trans pipe)
__device__ __forceinline__ float geluf(float x) {
    float x2 = x * x;
    float u  = __builtin_fmaf(0.044715f * x2, x, x);
    float e  = __builtin_amdgcn_exp2f(u * 2.30220795f);  // exp(2*0.79788456*u)
    return x * e * __builtin_amdgcn_rcpf(e + 1.0f);      // x*sigmoid(2y)
}

// ---------------- weight prep: f32 [K][N] -> bf16 [N][K] ----------------
__global__ void prep_weights(const float* __restrict__ W11, const float* __restrict__ W12,
                             const float* __restrict__ W13,
                             unsigned short* __restrict__ w11t, unsigned short* __restrict__ w12t,
                             unsigned short* __restrict__ w13t) {
    int idx = blockIdx.x * 256 + threadIdx.x;
    if (idx < 512 * 128) {
        int k = idx >> 7, n = idx & 127;
        w11t[n * 512 + k] = f2bf(W11[idx]);
    } else if (idx < 512 * 128 + 128 * 128) {
        int j = idx - 512 * 128;
        int k = j >> 7, n = j & 127;
        w12t[n * 128 + k] = f2bf(W12[j]);
    } else if (idx < 512 * 128 + 2 * 128 * 128) {
        int j = idx - (512 * 128 + 128 * 128);
        int k = j >> 7, n = j & 127;
        w13t[n * 128 + k] = f2bf(W13[j]);
    }
}

// ---------------- fused MLP + residual + BN partials ----------------
// 256 threads (4 waves), 32 KiB LDS -> 5 blocks/CU (exactly 160 KiB), 20 waves/CU.
// Each block processes TPB=4 tiles of 32 edges.
// LDS row layout (per edge, 1024B): [hV[src] | hE | hV[dst] | vff] bf16, XOR-swizzled
// in 16B chunks: stored chunk = (c & ~7) | ((c ^ row) & 7).
// After GEMM1, h1 overwrites the vff region (+768B), h2 overwrites hV[dst] (+512B).
template <int XBF16>
__global__ __launch_bounds__(256, 5) void edge_mlp_kernel(
    const float* __restrict__ hV, const float* __restrict__ hE,
    const int* __restrict__ eidx, const float* __restrict__ vff,
    const unsigned short* __restrict__ w11t, const unsigned short* __restrict__ w12t,
    const unsigned short* __restrict__ w13t,
    const float* __restrict__ b11, const float* __restrict__ b12, const float* __restrict__ b13,
    float* __restrict__ psum, float* __restrict__ psumsq,
    float* __restrict__ xf32, unsigned short* __restrict__ xbf16,
    int E)
{
    __shared__ __align__(16) char lds[BM * 1024];
    const int tid  = threadIdx.x;
    const int lane = tid & 63;
    const int wid  = tid >> 6;
    const int lr   = lane & 15;
    const int lh   = lane >> 4;

    // int64-vs-int32 edge_idx detection (int64 little-endian: odd 32b words are 0)
    const bool idx64 = ((eidx[1] | eidx[3] | eidx[5] | eidx[7]) == 0);

    const int n0 = wid * 32 + lr;   // this wave's two output columns
    const int n1 = n0 + 16;
    const float bv11_0 = b11[n0], bv11_1 = b11[n1];
    const float bv12_0 = b12[n0], bv12_1 = b12[n1];
    const float bv13_0 = b13[n0], bv13_1 = b13[n1];

    float s0 = 0.f, q0 = 0.f, s1 = 0.f, q1 = 0.f;   // BN partials across tiles

    const int cs  = lane;       // source 16B-chunk (8 f32 -> 8 bf16)
    const int seg = cs >> 4;
    const int cin = cs & 15;

    for (int t = 0; t < TPB; ++t) {
        const int e0 = (blockIdx.x * TPB + t) * BM;
        __syncthreads();   // previous iteration's LDS reads done before restage

        // ---- stage h_EV tile: 4 waves cover 4 rows/iter, lane covers one 16B chunk ----
        for (int it = 0; it < BM / 4; ++it) {
            int r = it * 4 + wid;
            int e = e0 + r;
            const float* sp;
            if (seg == 0) {
                int s = idx64 ? eidx[2 * e] : eidx[e];
                sp = hV + (size_t)s * HID + cin * 8;
            } else if (seg == 1) {
                sp = hE + (size_t)e * HID + cin * 8;
            } else if (seg == 2) {
                int d = idx64 ? eidx[2 * (E + e)] : eidx[E + e];
                sp = hV + (size_t)d * HID + cin * 8;
            } else {
                sp = vff + (size_t)e * HID + cin * 8;
            }
            f32x4 a = *(const f32x4*)sp;
            f32x4 b = *(const f32x4*)(sp + 4);
            u16x8 p;
            p[0] = f2bf(a[0]); p[1] = f2bf(a[1]); p[2] = f2bf(a[2]); p[3] = f2bf(a[3]);
            p[4] = f2bf(b[0]); p[5] = f2bf(b[1]); p[6] = f2bf(b[2]); p[7] = f2bf(b[3]);
            int cd = (cs & 56) | ((cs ^ r) & 7);
            *(u16x8*)(lds + r * 1024 + cd * 16) = p;
        }
        __syncthreads();

        f32x4 acc[2][2];
#pragma unroll
        for (int j = 0; j < 2; ++j)
#pragma unroll
            for (int m = 0; m < 2; ++m) acc[j][m] = (f32x4){0.f, 0.f, 0.f, 0.f};

        // ---- GEMM1: [32x512] @ [512x128] ----
        for (int kt = 0; kt < 16; ++kt) {
            bf16x8 b0 = *(const bf16x8*)(w11t + n0 * 512 + kt * 32 + lh * 8);
            bf16x8 b1 = *(const bf16x8*)(w11t + n1 * 512 + kt * 32 + lh * 8);
            int c = kt * 4 + lh;
#pragma unroll
            for (int m = 0; m < 2; ++m) {
                int row = m * 16 + lr;
                int cd  = (c & 56) | ((c ^ row) & 7);
                bf16x8 a = *(const bf16x8*)(lds + row * 1024 + cd * 16);
                acc[0][m] = __builtin_amdgcn_mfma_f32_16x16x32_bf16(a, b0, acc[0][m], 0, 0, 0);
                acc[1][m] = __builtin_amdgcn_mfma_f32_16x16x32_bf16(a, b1, acc[1][m], 0, 0, 0);
            }
        }
        __syncthreads();   // all GEMM1 LDS reads done before h1 overwrites vff region

        // ---- bias + GELU -> h1 into +768 region ----
#pragma unroll
        for (int m = 0; m < 2; ++m)
#pragma unroll
            for (int i = 0; i < 4; ++i) {
                int row = m * 16 + lh * 4 + i;
                float v0 = geluf(acc[0][m][i] + bv11_0);
                float v1 = geluf(acc[1][m][i] + bv11_1);
                int ch0 = n0 >> 3, ch1 = n1 >> 3;
                int sw0 = (ch0 & 8) | ((ch0 ^ row) & 7);
                int sw1 = (ch1 & 8) | ((ch1 ^ row) & 7);
                *(unsigned short*)(lds + row * 1024 + 768 + sw0 * 16 + (n0 & 7) * 2) = f2bf(v0);
                *(unsigned short*)(lds + row * 1024 + 768 + sw1 * 16 + (n1 & 7) * 2) = f2bf(v1);
            }
        __syncthreads();

        // ---- GEMM2: [32x128] @ [128x128] ----
#pragma unroll
        for (int j = 0; j < 2; ++j)
#pragma unroll
            for (int m = 0; m < 2; ++m) acc[j][m] = (f32x4){0.f, 0.f, 0.f, 0.f};
        for (int kt = 0; kt < 4; ++kt) {
            bf16x8 b0 = *(const bf16x8*)(w12t + n0 * 128 + kt * 32 + lh * 8);
            bf16x8 b1 = *(const bf16x8*)(w12t + n1 * 128 + kt * 32 + lh * 8);
            int c = kt * 4 + lh;
#pragma unroll
            for (int m = 0; m < 2; ++m) {
                int row = m * 16 + lr;
                int sw  = (c & 8) | ((c ^ row) & 7);
                bf16x8 a = *(const bf16x8*)(lds + row * 1024 + 768 + sw * 16);
                acc[0][m] = __builtin_amdgcn_mfma_f32_16x16x32_bf16(a, b0, acc[0][m], 0, 0, 0);
                acc[1][m] = __builtin_amdgcn_mfma_f32_16x16x32_bf16(a, b1, acc[1][m], 0, 0, 0);
            }
        }
        // h2 region (+512) disjoint from h1 region (+768): no barrier before write
#pragma unroll
        for (int m = 0; m < 2; ++m)
#pragma unroll
            for (int i = 0; i < 4; ++i) {
                int row = m * 16 + lh * 4 + i;
                float v0 = geluf(acc[0][m][i] + bv12_0);
                float v1 = geluf(acc[1][m][i] + bv12_1);
                int ch0 = n0 >> 3, ch1 = n1 >> 3;
                int sw0 = (ch0 & 8) | ((ch0 ^ row) & 7);
                int sw1 = (ch1 & 8) | ((ch1 ^ row) & 7);
                *(unsigned short*)(lds + row * 1024 + 512 + sw0 * 16 + (n0 & 7) * 2) = f2bf(v0);
                *(unsigned short*)(lds + row * 1024 + 512 + sw1 * 16 + (n1 & 7) * 2) = f2bf(v1);
            }
        __syncthreads();

        // ---- GEMM3: [32x128] @ [128x128] ----
#pragma unroll
        for (int j = 0; j < 2; ++j)
#pragma unroll
            for (int m = 0; m < 2; ++m) acc[j][m] = (f32x4){0.f, 0.f, 0.f, 0.f};
        for (int kt = 0; kt < 4; ++kt) {
            bf16x8 b0 = *(const bf16x8*)(w13t + n0 * 128 + kt * 32 + lh * 8);
            bf16x8 b1 = *(const bf16x8*)(w13t + n1 * 128 + kt * 32 + lh * 8);
            int c = kt * 4 + lh;
#pragma unroll
            for (int m = 0; m < 2; ++m) {
                int row = m * 16 + lr;
                int sw  = (c & 8) | ((c ^ row) & 7);
                bf16x8 a = *(const bf16x8*)(lds + row * 1024 + 512 + sw * 16);
                acc[0][m] = __builtin_amdgcn_mfma_f32_16x16x32_bf16(a, b0, acc[0][m], 0, 0, 0);
                acc[1][m] = __builtin_amdgcn_mfma_f32_16x16x32_bf16(a, b1, acc[1][m], 0, 0, 0);
            }
        }

        // ---- epilogue: +b13, +h_E residual (LDS +256), write x, accumulate BN partials ----
#pragma unroll
        for (int m = 0; m < 2; ++m)
#pragma unroll
            for (int i = 0; i < 4; ++i) {
                int row = m * 16 + lh * 4 + i;
                size_t e = (size_t)(e0 + row);
                int c0 = 16 + (n0 >> 3);
                int c1 = 16 + (n1 >> 3);
                int d0 = (c0 & 56) | ((c0 ^ row) & 7);
                int d1 = (c1 & 56) | ((c1 ^ row) & 7);
                float he0 = bf2f(*(unsigned short*)(lds + row * 1024 + d0 * 16 + (n0 & 7) * 2));
                float he1 = bf2f(*(unsigned short*)(lds + row * 1024 + d1 * 16 + (n1 & 7) * 2));
                float x0 = acc[0][m][i] + bv13_0 + he0;
                float x1 = acc[1][m][i] + bv13_1 + he1;
                s0 += x0; q0 += x0 * x0;
                s1 += x1; q1 += x1 * x1;
                if (XBF16) {
                    xbf16[e * HID + n0] = f2bf(x0);
                    xbf16[e * HID + n1] = f2bf(x1);
                } else {
                    xf32[e * HID + n0] = x0;
                    xf32[e * HID + n1] = x1;
                }
            }
    }

    // ---- one partial-sum write per block ----
    s0 += __shfl_xor(s0, 16); s0 += __shfl_xor(s0, 32);
    q0 += __shfl_xor(q0, 16); q0 += __shfl_xor(q0, 32);
    s1 += __shfl_xor(s1, 16); s1 += __shfl_xor(s1, 32);
    q1 += __shfl_xor(q1, 16); q1 += __shfl_xor(q1, 32);
    if (lane < 16) {
        size_t base = (size_t)blockIdx.x * HID;
        psum[base + n0]   = s0;
        psum[base + n1]   = s1;
        psumsq[base + n0] = q0;
        psumsq[base + n1] = q1;
    }
}

// ---------------- BN stats: reduce per-block partials -> scale/shift ----------------
__global__ void bn_stats_kernel(const float* __restrict__ psum, const float* __restrict__ psumsq,
                                const float* __restrict__ gamma, const float* __restrict__ beta,
                                float* __restrict__ params, int nblk, float invE) {
    int c = blockIdx.x;   // channel 0..127
    float s = 0.f, q = 0.f;
    for (int i = threadIdx.x; i < nblk; i += 256) {
        s += psum[(size_t)i * 128 + c];
        q += psumsq[(size_t)i * 128 + c];
    }
#pragma unroll
    for (int o = 1; o < 64; o <<= 1) { s += __shfl_xor(s, o); q += __shfl_xor(q, o); }
    __shared__ float as[4], aq[4];
    int w = threadIdx.x >> 6;
    if ((threadIdx.x & 63) == 0) { as[w] = s; aq[w] = q; }
    __syncthreads();
    if (threadIdx.x == 0) {
        float S  = as[0] + as[1] + as[2] + as[3];
        float Q  = aq[0] + aq[1] + aq[2] + aq[3];
        float mean = S * invE;
        float var  = Q * invE - mean * mean;
        float sc   = gamma[c] * rsqrtf(var + 1e-5f);
        params[c]       = sc;
        params[128 + c] = beta[c] - mean * sc;
    }
}

// ---------------- BN apply ----------------
__global__ void bn_apply_bf16(const unsigned short* __restrict__ x, float* __restrict__ out,
                              const float* __restrict__ params, int total8) {
    __shared__ float sc[128], sh[128];
    if (threadIdx.x < 128) { sc[threadIdx.x] = params[threadIdx.x]; sh[threadIdx.x] = params[128 + threadIdx.x]; }
    __syncthreads();
    int stride = gridDim.x * blockDim.x;
    for (int i = blockIdx.x * blockDim.x + threadIdx.x; i < total8; i += stride) {
        size_t base = (size_t)i * 8;
        u16x8 v = *(const u16x8*)(x + base);
        int c0 = (int)(base & 127);
        f32x4 o0, o1;
#pragma unroll
        for (int e = 0; e < 4; ++e) o0[e] = bf2f(v[e]) * sc[c0 + e] + sh[c0 + e];
#pragma unroll
        for (int e = 0; e < 4; ++e) o1[e] = bf2f(v[4 + e]) * sc[c0 + 4 + e] + sh[c0 + 4 + e];
        *(f32x4*)(out + base)     = o0;
        *(f32x4*)(out + base + 4) = o1;
    }
}

__global__ void bn_apply_f32(float* __restrict__ x, const float* __restrict__ params, int total4) {
    __shared__ float sc[128], sh[128];
    if (threadIdx.x < 128) { sc[threadIdx.x] = params[threadIdx.x]; sh[threadIdx.x] = params[128 + threadIdx.x]; }
    __syncthreads();
    int stride = gridDim.x * blockDim.x;
    for (int i = blockIdx.x * blockDim.x + threadIdx.x; i < total4; i += stride) {
        size_t base = (size_t)i * 4;
        f32x4 v = *(f32x4*)(x + base);
        int c0 = (int)(base & 127);
#pragma unroll
        for (int e = 0; e < 4; ++e) v[e] = v[e] * sc[c0 + e] + sh[c0 + e];
        *(f32x4*)(x + base) = v;
    }
}

extern "C" void kernel_launch(void* const* d_in, const int* in_sizes, int n_in,
                              void* d_out, int out_size, void* d_ws, size_t ws_size,
                              hipStream_t stream) {
    const float* hV    = (const float*)d_in[0];
    const float* hE    = (const float*)d_in[1];
    const int*   eidx  = (const int*)d_in[2];
    const float* vff   = (const float*)d_in[4];
    const float* W11   = (const float*)d_in[5];
    const float* b11   = (const float*)d_in[6];
    const float* W12   = (const float*)d_in[7];
    const float* b12   = (const float*)d_in[8];
    const float* W13   = (const float*)d_in[9];
    const float* b13   = (const float*)d_in[10];
    const float* gamma = (const float*)d_in[11];
    const float* beta  = (const float*)d_in[12];

    const int E    = in_sizes[1] / HID;
    const int nblk = E / (BM * TPB);   // 400000/128 = 3125

    float* psum   = (float*)d_ws;
    float* psumsq = psum + (size_t)nblk * HID;
    float* params = psumsq + (size_t)nblk * HID;
    unsigned short* w11t = (unsigned short*)(params + 256);
    unsigned short* w12t = w11t + 512 * 128;
    unsigned short* w13t = w12t + 128 * 128;
    size_t xoff = ((size_t)((char*)(w13t + 128 * 128) - (char*)d_ws) + 15) & ~(size_t)15;
    unsigned short* xbf = (unsigned short*)((char*)d_ws + xoff);
    const bool useBf = ws_size >= xoff + (size_t)E * HID * 2;

    prep_weights<<<384, 256, 0, stream>>>(W11, W12, W13, w11t, w12t, w13t);

    if (useBf)
        edge_mlp_kernel<1><<<nblk, 256, 0, stream>>>(hV, hE, eidx, vff, w11t, w12t, w13t,
                                                     b11, b12, b13, psum, psumsq,
                                                     (float*)d_out, xbf, E);
    else
        edge_mlp_kernel<0><<<nblk, 256, 0, stream>>>(hV, hE, eidx, vff, w11t, w12t, w13t,
                                                     b11, b12, b13, psum, psumsq,
                                                     (float*)d_out, xbf, E);

    bn_stats_kernel<<<128, 256, 0, stream>>>(psum, psumsq, gamma, beta, params, nblk,
                                             1.0f / (float)E);

    if (useBf)
        bn_apply_bf16<<<2048, 256, 0, stream>>>(xbf, (float*)d_out, params, E * HID / 8);
    else
        bn_apply_f32<<<2048, 256, 0, stream>>>((float*)d_out, params, E * HID / 4);
}

// Round 3
// 564.015 us; speedup vs baseline: 1.8706x; 1.8706x over previous
//
#include <hip/hip_runtime.h>
#include <math.h>

typedef __attribute__((ext_vector_type(8))) short  bf16x8;
typedef __attribute__((ext_vector_type(4))) float  f32x4;
typedef __attribute__((ext_vector_type(8))) unsigned short u16x8;

#define HID 128
#define BM  32      // edges per block

__device__ __forceinline__ unsigned short f2bf(float f) {
    union { float f; unsigned u; } v; v.f = f;
    unsigned u = v.u;
    return (unsigned short)((u + 0x7fffu + ((u >> 16) & 1u)) >> 16);
}
__device__ __forceinline__ float bf2f(unsigned short h) {
    union { unsigned u; float f; } v; v.u = ((unsigned)h) << 16;
    return v.f;
}
// tanh-form GELU: max |diff vs exact| ~3e-4, ~9 VALU ops (2 on trans pipe)
__device__ __forceinline__ float geluf(float x) {
    float x2 = x * x;
    float u  = __builtin_fmaf(0.044715f * x2, x, x);
    float e  = __builtin_amdgcn_exp2f(u * 2.30220795f);  // exp(2*0.79788456*u)
    return x * e * __builtin_amdgcn_rcpf(e + 1.0f);      // x*sigmoid(2y)
}

// ---------------- weight prep: f32 [K][N] -> bf16 [N][K] ----------------
__global__ void prep_weights(const float* __restrict__ W11, const float* __restrict__ W12,
                             const float* __restrict__ W13,
                             unsigned short* __restrict__ w11t, unsigned short* __restrict__ w12t,
                             unsigned short* __restrict__ w13t) {
    int idx = blockIdx.x * 256 + threadIdx.x;
    if (idx < 512 * 128) {
        int k = idx >> 7, n = idx & 127;
        w11t[n * 512 + k] = f2bf(W11[idx]);
    } else if (idx < 512 * 128 + 128 * 128) {
        int j = idx - 512 * 128;
        int k = j >> 7, n = j & 127;
        w12t[n * 128 + k] = f2bf(W12[j]);
    } else if (idx < 512 * 128 + 2 * 128 * 128) {
        int j = idx - (512 * 128 + 128 * 128);
        int k = j >> 7, n = j & 127;
        w13t[n * 128 + k] = f2bf(W13[j]);
    }
}

// ---------------- fused MLP + residual + BN partials ----------------
// 256 threads (4 waves), 32 KiB LDS, __launch_bounds__(256,4):
// VGPR budget 128 (no spill; round-2's (256,5)=102 budget spilled -> 1.9 GB
// scratch traffic), LDS allows 5 blocks/CU, VGPR caps at 4 -> 16 waves/CU.
// One 32-edge tile per block, 12500 blocks.
// LDS row layout (per edge, 1024B): [hV[src] | hE | hV[dst] | vff] bf16, XOR-swizzled
// in 16B chunks: stored chunk = (c & ~7) | ((c ^ row) & 7).
// After GEMM1, h1 overwrites the vff region (+768B), h2 overwrites hV[dst] (+512B).
template <int XBF16>
__global__ __launch_bounds__(256, 4) void edge_mlp_kernel(
    const float* __restrict__ hV, const float* __restrict__ hE,
    const int* __restrict__ eidx, const float* __restrict__ vff,
    const unsigned short* __restrict__ w11t, const unsigned short* __restrict__ w12t,
    const unsigned short* __restrict__ w13t,
    const float* __restrict__ b11, const float* __restrict__ b12, const float* __restrict__ b13,
    float* __restrict__ psum, float* __restrict__ psumsq,
    float* __restrict__ xf32, unsigned short* __restrict__ xbf16,
    int E)
{
    __shared__ __align__(16) char lds[BM * 1024];
    const int tid  = threadIdx.x;
    const int lane = tid & 63;
    const int wid  = tid >> 6;
    const int lr   = lane & 15;
    const int lh   = lane >> 4;
    const int e0   = blockIdx.x * BM;

    // int64-vs-int32 edge_idx detection (int64 little-endian: odd 32b words are 0)
    const bool idx64 = ((eidx[1] | eidx[3] | eidx[5] | eidx[7]) == 0);

    const int n0 = wid * 32 + lr;   // this wave's two output columns
    const int n1 = n0 + 16;

    // ---- stage h_EV tile: 4 waves cover 4 rows/iter, lane covers one 16B chunk ----
    const int cs  = lane;       // source 16B-chunk (8 f32 -> 8 bf16)
    const int seg = cs >> 4;
    const int cin = cs & 15;
    for (int it = 0; it < BM / 4; ++it) {
        int r = it * 4 + wid;
        int e = e0 + r;
        const float* sp;
        if (seg == 0) {
            int s = idx64 ? eidx[2 * e] : eidx[e];
            sp = hV + (size_t)s * HID + cin * 8;
        } else if (seg == 1) {
            sp = hE + (size_t)e * HID + cin * 8;
        } else if (seg == 2) {
            int d = idx64 ? eidx[2 * (E + e)] : eidx[E + e];
            sp = hV + (size_t)d * HID + cin * 8;
        } else {
            sp = vff + (size_t)e * HID + cin * 8;
        }
        f32x4 a = *(const f32x4*)sp;
        f32x4 b = *(const f32x4*)(sp + 4);
        u16x8 p;
        p[0] = f2bf(a[0]); p[1] = f2bf(a[1]); p[2] = f2bf(a[2]); p[3] = f2bf(a[3]);
        p[4] = f2bf(b[0]); p[5] = f2bf(b[1]); p[6] = f2bf(b[2]); p[7] = f2bf(b[3]);
        int cd = (cs & 56) | ((cs ^ r) & 7);
        *(u16x8*)(lds + r * 1024 + cd * 16) = p;
    }
    __syncthreads();

    f32x4 acc[2][2];
#pragma unroll
    for (int j = 0; j < 2; ++j)
#pragma unroll
        for (int m = 0; m < 2; ++m) acc[j][m] = (f32x4){0.f, 0.f, 0.f, 0.f};

    // ---- GEMM1: [32x512] @ [512x128] ----
    for (int kt = 0; kt < 16; ++kt) {
        bf16x8 b0 = *(const bf16x8*)(w11t + n0 * 512 + kt * 32 + lh * 8);
        bf16x8 b1 = *(const bf16x8*)(w11t + n1 * 512 + kt * 32 + lh * 8);
        int c = kt * 4 + lh;
#pragma unroll
        for (int m = 0; m < 2; ++m) {
            int row = m * 16 + lr;
            int cd  = (c & 56) | ((c ^ row) & 7);
            bf16x8 a = *(const bf16x8*)(lds + row * 1024 + cd * 16);
            acc[0][m] = __builtin_amdgcn_mfma_f32_16x16x32_bf16(a, b0, acc[0][m], 0, 0, 0);
            acc[1][m] = __builtin_amdgcn_mfma_f32_16x16x32_bf16(a, b1, acc[1][m], 0, 0, 0);
        }
    }
    __syncthreads();   // all GEMM1 LDS reads done before h1 overwrites vff region

    // ---- bias + GELU -> h1 into +768 region ----
    {
        float bv0 = b11[n0], bv1 = b11[n1];
#pragma unroll
        for (int m = 0; m < 2; ++m)
#pragma unroll
            for (int i = 0; i < 4; ++i) {
                int row = m * 16 + lh * 4 + i;
                float v0 = geluf(acc[0][m][i] + bv0);
                float v1 = geluf(acc[1][m][i] + bv1);
                int ch0 = n0 >> 3, ch1 = n1 >> 3;
                int sw0 = (ch0 & 8) | ((ch0 ^ row) & 7);
                int sw1 = (ch1 & 8) | ((ch1 ^ row) & 7);
                *(unsigned short*)(lds + row * 1024 + 768 + sw0 * 16 + (n0 & 7) * 2) = f2bf(v0);
                *(unsigned short*)(lds + row * 1024 + 768 + sw1 * 16 + (n1 & 7) * 2) = f2bf(v1);
            }
    }
    __syncthreads();

    // ---- GEMM2: [32x128] @ [128x128] ----
#pragma unroll
    for (int j = 0; j < 2; ++j)
#pragma unroll
        for (int m = 0; m < 2; ++m) acc[j][m] = (f32x4){0.f, 0.f, 0.f, 0.f};
    for (int kt = 0; kt < 4; ++kt) {
        bf16x8 b0 = *(const bf16x8*)(w12t + n0 * 128 + kt * 32 + lh * 8);
        bf16x8 b1 = *(const bf16x8*)(w12t + n1 * 128 + kt * 32 + lh * 8);
        int c = kt * 4 + lh;
#pragma unroll
        for (int m = 0; m < 2; ++m) {
            int row = m * 16 + lr;
            int sw  = (c & 8) | ((c ^ row) & 7);
            bf16x8 a = *(const bf16x8*)(lds + row * 1024 + 768 + sw * 16);
            acc[0][m] = __builtin_amdgcn_mfma_f32_16x16x32_bf16(a, b0, acc[0][m], 0, 0, 0);
            acc[1][m] = __builtin_amdgcn_mfma_f32_16x16x32_bf16(a, b1, acc[1][m], 0, 0, 0);
        }
    }
    // h2 region (+512) disjoint from h1 region (+768): no barrier before write
    {
        float bv0 = b12[n0], bv1 = b12[n1];
#pragma unroll
        for (int m = 0; m < 2; ++m)
#pragma unroll
            for (int i = 0; i < 4; ++i) {
                int row = m * 16 + lh * 4 + i;
                float v0 = geluf(acc[0][m][i] + bv0);
                float v1 = geluf(acc[1][m][i] + bv1);
                int ch0 = n0 >> 3, ch1 = n1 >> 3;
                int sw0 = (ch0 & 8) | ((ch0 ^ row) & 7);
                int sw1 = (ch1 & 8) | ((ch1 ^ row) & 7);
                *(unsigned short*)(lds + row * 1024 + 512 + sw0 * 16 + (n0 & 7) * 2) = f2bf(v0);
                *(unsigned short*)(lds + row * 1024 + 512 + sw1 * 16 + (n1 & 7) * 2) = f2bf(v1);
            }
    }
    __syncthreads();

    // ---- GEMM3: [32x128] @ [128x128] ----
#pragma unroll
    for (int j = 0; j < 2; ++j)
#pragma unroll
        for (int m = 0; m < 2; ++m) acc[j][m] = (f32x4){0.f, 0.f, 0.f, 0.f};
    for (int kt = 0; kt < 4; ++kt) {
        bf16x8 b0 = *(const bf16x8*)(w13t + n0 * 128 + kt * 32 + lh * 8);
        bf16x8 b1 = *(const bf16x8*)(w13t + n1 * 128 + kt * 32 + lh * 8);
        int c = kt * 4 + lh;
#pragma unroll
        for (int m = 0; m < 2; ++m) {
            int row = m * 16 + lr;
            int sw  = (c & 8) | ((c ^ row) & 7);
            bf16x8 a = *(const bf16x8*)(lds + row * 1024 + 512 + sw * 16);
            acc[0][m] = __builtin_amdgcn_mfma_f32_16x16x32_bf16(a, b0, acc[0][m], 0, 0, 0);
            acc[1][m] = __builtin_amdgcn_mfma_f32_16x16x32_bf16(a, b1, acc[1][m], 0, 0, 0);
        }
    }

    // ---- epilogue: +b13, +h_E residual (LDS +256), write x, BN partials ----
    {
        float bv0 = b13[n0], bv1 = b13[n1];
        float s0 = 0.f, q0 = 0.f, s1 = 0.f, q1 = 0.f;
#pragma unroll
        for (int m = 0; m < 2; ++m)
#pragma unroll
            for (int i = 0; i < 4; ++i) {
                int row = m * 16 + lh * 4 + i;
                size_t e = (size_t)(e0 + row);
                int c0 = 16 + (n0 >> 3);
                int c1 = 16 + (n1 >> 3);
                int d0 = (c0 & 56) | ((c0 ^ row) & 7);
                int d1 = (c1 & 56) | ((c1 ^ row) & 7);
                float he0 = bf2f(*(unsigned short*)(lds + row * 1024 + d0 * 16 + (n0 & 7) * 2));
                float he1 = bf2f(*(unsigned short*)(lds + row * 1024 + d1 * 16 + (n1 & 7) * 2));
                float x0 = acc[0][m][i] + bv0 + he0;
                float x1 = acc[1][m][i] + bv1 + he1;
                s0 += x0; q0 += x0 * x0;
                s1 += x1; q1 += x1 * x1;
                if (XBF16) {
                    xbf16[e * HID + n0] = f2bf(x0);
                    xbf16[e * HID + n1] = f2bf(x1);
                } else {
                    xf32[e * HID + n0] = x0;
                    xf32[e * HID + n1] = x1;
                }
            }
        s0 += __shfl_xor(s0, 16); s0 += __shfl_xor(s0, 32);
        q0 += __shfl_xor(q0, 16); q0 += __shfl_xor(q0, 32);
        s1 += __shfl_xor(s1, 16); s1 += __shfl_xor(s1, 32);
        q1 += __shfl_xor(q1, 16); q1 += __shfl_xor(q1, 32);
        if (lane < 16) {
            size_t base = (size_t)blockIdx.x * HID;
            psum[base + n0]   = s0;
            psum[base + n1]   = s1;
            psumsq[base + n0] = q0;
            psumsq[base + n1] = q1;
        }
    }
}

// ---------------- BN stats: reduce per-block partials -> scale/shift ----------------
__global__ void bn_stats_kernel(const float* __restrict__ psum, const float* __restrict__ psumsq,
                                const float* __restrict__ gamma, const float* __restrict__ beta,
                                float* __restrict__ params, int nblk, float invE) {
    int c = blockIdx.x;   // channel 0..127
    float s = 0.f, q = 0.f;
    for (int i = threadIdx.x; i < nblk; i += 256) {
        s += psum[(size_t)i * 128 + c];
        q += psumsq[(size_t)i * 128 + c];
    }
#pragma unroll
    for (int o = 1; o < 64; o <<= 1) { s += __shfl_xor(s, o); q += __shfl_xor(q, o); }
    __shared__ float as[4], aq[4];
    int w = threadIdx.x >> 6;
    if ((threadIdx.x & 63) == 0) { as[w] = s; aq[w] = q; }
    __syncthreads();
    if (threadIdx.x == 0) {
        float S  = as[0] + as[1] + as[2] + as[3];
        float Q  = aq[0] + aq[1] + aq[2] + aq[3];
        float mean = S * invE;
        float var  = Q * invE - mean * mean;
        float sc   = gamma[c] * rsqrtf(var + 1e-5f);
        params[c]       = sc;
        params[128 + c] = beta[c] - mean * sc;
    }
}

// ---------------- BN apply ----------------
__global__ void bn_apply_bf16(const unsigned short* __restrict__ x, float* __restrict__ out,
                              const float* __restrict__ params, int total8) {
    __shared__ float sc[128], sh[128];
    if (threadIdx.x < 128) { sc[threadIdx.x] = params[threadIdx.x]; sh[threadIdx.x] = params[128 + threadIdx.x]; }
    __syncthreads();
    int stride = gridDim.x * blockDim.x;
    for (int i = blockIdx.x * blockDim.x + threadIdx.x; i < total8; i += stride) {
        size_t base = (size_t)i * 8;
        u16x8 v = *(const u16x8*)(x + base);
        int c0 = (int)(base & 127);
        f32x4 o0, o1;
#pragma unroll
        for (int e = 0; e < 4; ++e) o0[e] = bf2f(v[e]) * sc[c0 + e] + sh[c0 + e];
#pragma unroll
        for (int e = 0; e < 4; ++e) o1[e] = bf2f(v[4 + e]) * sc[c0 + 4 + e] + sh[c0 + 4 + e];
        *(f32x4*)(out + base)     = o0;
        *(f32x4*)(out + base + 4) = o1;
    }
}

__global__ void bn_apply_f32(float* __restrict__ x, const float* __restrict__ params, int total4) {
    __shared__ float sc[128], sh[128];
    if (threadIdx.x < 128) { sc[threadIdx.x] = params[threadIdx.x]; sh[threadIdx.x] = params[128 + threadIdx.x]; }
    __syncthreads();
    int stride = gridDim.x * blockDim.x;
    for (int i = blockIdx.x * blockDim.x + threadIdx.x; i < total4; i += stride) {
        size_t base = (size_t)i * 4;
        f32x4 v = *(f32x4*)(x + base);
        int c0 = (int)(base & 127);
#pragma unroll
        for (int e = 0; e < 4; ++e) v[e] = v[e] * sc[c0 + e] + sh[c0 + e];
        *(f32x4*)(x + base) = v;
    }
}

extern "C" void kernel_launch(void* const* d_in, const int* in_sizes, int n_in,
                              void* d_out, int out_size, void* d_ws, size_t ws_size,
                              hipStream_t stream) {
    const float* hV    = (const float*)d_in[0];
    const float* hE    = (const float*)d_in[1];
    const int*   eidx  = (const int*)d_in[2];
    const float* vff   = (const float*)d_in[4];
    const float* W11   = (const float*)d_in[5];
    const float* b11   = (const float*)d_in[6];
    const float* W12   = (const float*)d_in[7];
    const float* b12   = (const float*)d_in[8];
    const float* W13   = (const float*)d_in[9];
    const float* b13   = (const float*)d_in[10];
    const float* gamma = (const float*)d_in[11];
    const float* beta  = (const float*)d_in[12];

    const int E    = in_sizes[1] / HID;
    const int nblk = E / BM;   // 400000/32 = 12500

    float* psum   = (float*)d_ws;
    float* psumsq = psum + (size_t)nblk * HID;
    float* params = psumsq + (size_t)nblk * HID;
    unsigned short* w11t = (unsigned short*)(params + 256);
    unsigned short* w12t = w11t + 512 * 128;
    unsigned short* w13t = w12t + 128 * 128;
    size_t xoff = ((size_t)((char*)(w13t + 128 * 128) - (char*)d_ws) + 15) & ~(size_t)15;
    unsigned short* xbf = (unsigned short*)((char*)d_ws + xoff);
    const bool useBf = ws_size >= xoff + (size_t)E * HID * 2;

    prep_weights<<<384, 256, 0, stream>>>(W11, W12, W13, w11t, w12t, w13t);

    if (useBf)
        edge_mlp_kernel<1><<<nblk, 256, 0, stream>>>(hV, hE, eidx, vff, w11t, w12t, w13t,
                                                     b11, b12, b13, psum, psumsq,
                                                     (float*)d_out, xbf, E);
    else
        edge_mlp_kernel<0><<<nblk, 256, 0, stream>>>(hV, hE, eidx, vff, w11t, w12t, w13t,
                                                     b11, b12, b13, psum, psumsq,
                                                     (float*)d_out, xbf, E);

    bn_stats_kernel<<<128, 256, 0, stream>>>(psum, psumsq, gamma, beta, params, nblk,
                                             1.0f / (float)E);

    if (useBf)
        bn_apply_bf16<<<2048, 256, 0, stream>>>(xbf, (float*)d_out, params, E * HID / 8);
    else
        bn_apply_f32<<<2048, 256, 0, stream>>>((float*)d_out, params, E * HID / 4);
}

// Round 4
// 501.988 us; speedup vs baseline: 2.1017x; 1.1236x over previous
//
#include <hip/hip_runtime.h>
#include <hip/hip_bf16.h>
#include <math.h>

typedef __attribute__((ext_vector_type(8))) short  bf16x8;
typedef __attribute__((ext_vector_type(4))) float  f32x4;
typedef __attribute__((ext_vector_type(8))) unsigned short u16x8;

#define HID 128
#define BM  32      // edges per block

__device__ __forceinline__ unsigned short f2bf(float f) {
    union { float f; unsigned u; } v; v.f = f;
    unsigned u = v.u;
    return (unsigned short)((u + 0x7fffu + ((u >> 16) & 1u)) >> 16);
}
__device__ __forceinline__ unsigned pkbf(float a, float b) {
    __hip_bfloat162 h2 = __float22bfloat162_rn(float2{a, b});
    union { __hip_bfloat162 h; unsigned u; } u; u.h = h2; return u.u;
}
__device__ __forceinline__ unsigned short bfr(float f) {
    __hip_bfloat16 h = __float2bfloat16(f);
    union { __hip_bfloat16 h; unsigned short s; } u; u.h = h; return u.s;
}
__device__ __forceinline__ float bf2f(unsigned short h) {
    union { unsigned u; float f; } v; v.u = ((unsigned)h) << 16;
    return v.f;
}
// tanh-form GELU: max |diff vs exact| ~3e-4
__device__ __forceinline__ float geluf(float x) {
    float x2 = x * x;
    float u  = __builtin_fmaf(0.044715f * x2, x, x);
    float e  = __builtin_amdgcn_exp2f(u * 2.30220795f);  // exp(2*0.79788456*u)
    return x * e * __builtin_amdgcn_rcpf(e + 1.0f);      // x*sigmoid(2y)
}

// ---------------- weight prep: f32 [K][N] -> bf16 [N][K] ----------------
__global__ void prep_weights(const float* __restrict__ W11, const float* __restrict__ W12,
                             const float* __restrict__ W13,
                             unsigned short* __restrict__ w11t, unsigned short* __restrict__ w12t,
                             unsigned short* __restrict__ w13t) {
    int idx = blockIdx.x * 256 + threadIdx.x;
    if (idx < 512 * 128) {
        int k = idx >> 7, n = idx & 127;
        w11t[n * 512 + k] = f2bf(W11[idx]);
    } else if (idx < 512 * 128 + 128 * 128) {
        int j = idx - 512 * 128;
        int k = j >> 7, n = j & 127;
        w12t[n * 128 + k] = f2bf(W12[j]);
    } else if (idx < 512 * 128 + 2 * 128 * 128) {
        int j = idx - (512 * 128 + 128 * 128);
        int k = j >> 7, n = j & 127;
        w13t[n * 128 + k] = f2bf(W13[j]);
    }
}

// ---------------- fused MLP + residual + BN partials ----------------
// 256 threads (4 waves), 32 KiB LDS, __launch_bounds__(256,4): 4 blocks/CU.
// Streaming data (hE, vff, x) uses non-temporal loads/stores so L2 keeps
// weights + hV hot. Weight loads explicitly double-buffered in registers
// (16 loads in flight for GEMM1; GEMM2/3 fragments prefetched a phase early).
// LDS row layout (per edge, 1024B): [hV[src] | hE | hV[dst] | vff] bf16,
// XOR-swizzled in 16B chunks: stored chunk = (c & ~7) | ((c ^ row) & 7).
// After GEMM1, h1 overwrites vff region (+768B), h2 overwrites hV[dst] (+512B).
template <int XBF16>
__global__ __launch_bounds__(256, 4) void edge_mlp_kernel(
    const float* __restrict__ hV, const float* __restrict__ hE,
    const int* __restrict__ eidx, const float* __restrict__ vff,
    const unsigned short* __restrict__ w11t, const unsigned short* __restrict__ w12t,
    const unsigned short* __restrict__ w13t,
    const float* __restrict__ b11, const float* __restrict__ b12, const float* __restrict__ b13,
    float* __restrict__ psum, float* __restrict__ psumsq,
    float* __restrict__ xf32, unsigned short* __restrict__ xbf16,
    int E)
{
    __shared__ __align__(16) char lds[BM * 1024];
    const int tid  = threadIdx.x;
    const int lane = tid & 63;
    const int wid  = tid >> 6;
    const int lr   = lane & 15;
    const int lh   = lane >> 4;
    const int e0   = blockIdx.x * BM;

    // int64-vs-int32 edge_idx detection (int64 little-endian: odd 32b words are 0)
    const bool idx64 = ((eidx[1] | eidx[3] | eidx[5] | eidx[7]) == 0);

    const int n0 = wid * 32 + lr;   // this wave's two output columns
    const int n1 = n0 + 16;

    const int cs  = lane;       // source 16B-chunk (8 f32 -> 8 bf16)
    const int seg = cs >> 4;
    const int cin = cs & 15;

    auto stage_src = [&](int it) -> const float* {
        int r = it * 4 + wid, e = e0 + r;
        const float* sp;
        if (seg == 0)      { int s = idx64 ? eidx[2 * e] : eidx[e];             sp = hV  + (size_t)s * HID + cin * 8; }
        else if (seg == 1) { sp = hE  + (size_t)e * HID + cin * 8; }
        else if (seg == 2) { int d = idx64 ? eidx[2 * (E + e)] : eidx[E + e];   sp = hV  + (size_t)d * HID + cin * 8; }
        else               { sp = vff + (size_t)e * HID + cin * 8; }
        return sp;
    };
    auto write_lds = [&](int it, const f32x4* v) {
        int r = it * 4 + wid;
        union { u16x8 s; unsigned u[4]; } p;
        p.u[0] = pkbf(v[0][0], v[0][1]); p.u[1] = pkbf(v[0][2], v[0][3]);
        p.u[2] = pkbf(v[1][0], v[1][1]); p.u[3] = pkbf(v[1][2], v[1][3]);
        int cd = (cs & 56) | ((cs ^ r) & 7);
        *(u16x8*)(lds + r * 1024 + cd * 16) = p.s;
    };

    // ---- stage h_EV tile: two 8-load groups in flight, then convert+write ----
    {
        const bool ntl = (seg & 1);   // hE/vff are streamed once: keep out of L2
        f32x4 ra[4][2], rb[4][2];
#pragma unroll
        for (int it = 0; it < 4; ++it) {
            const float* sp = stage_src(it);
            if (ntl) { ra[it][0] = __builtin_nontemporal_load((const f32x4*)sp);
                       ra[it][1] = __builtin_nontemporal_load(((const f32x4*)sp) + 1); }
            else     { ra[it][0] = *(const f32x4*)sp;
                       ra[it][1] = *(((const f32x4*)sp) + 1); }
        }
#pragma unroll
        for (int it = 0; it < 4; ++it) {
            const float* sp = stage_src(it + 4);
            if (ntl) { rb[it][0] = __builtin_nontemporal_load((const f32x4*)sp);
                       rb[it][1] = __builtin_nontemporal_load(((const f32x4*)sp) + 1); }
            else     { rb[it][0] = *(const f32x4*)sp;
                       rb[it][1] = *(((const f32x4*)sp) + 1); }
        }
#pragma unroll
        for (int it = 0; it < 4; ++it) write_lds(it, ra[it]);
#pragma unroll
        for (int it = 0; it < 4; ++it) write_lds(it + 4, rb[it]);
    }
    __syncthreads();

    f32x4 acc[2][2];
#pragma unroll
    for (int j = 0; j < 2; ++j)
#pragma unroll
        for (int m = 0; m < 2; ++m) acc[j][m] = (f32x4){0.f, 0.f, 0.f, 0.f};

    const unsigned short* wp0  = w11t + n0 * 512 + lh * 8;
    const unsigned short* wp1  = w11t + n1 * 512 + lh * 8;
    const unsigned short* wq20 = w12t + n0 * 128 + lh * 8;
    const unsigned short* wq21 = w12t + n1 * 128 + lh * 8;
    const unsigned short* wq30 = w13t + n0 * 128 + lh * 8;
    const unsigned short* wq31 = w13t + n1 * 128 + lh * 8;

    bf16x8 bA[4][2], bB[4][2], b2[4][2], b3[4][2];

#define PREF4(buf, q0, q1, base) \
    { _Pragma("unroll") for (int j = 0; j < 4; ++j) { \
        buf[j][0] = *(const bf16x8*)((q0) + ((base) + j) * 32); \
        buf[j][1] = *(const bf16x8*)((q1) + ((base) + j) * 32); } }

#define CONS4_G1(buf, base) \
    { _Pragma("unroll") for (int j = 0; j < 4; ++j) { \
        int c = ((base) + j) * 4 + lh; \
        _Pragma("unroll") for (int m = 0; m < 2; ++m) { \
            int row = m * 16 + lr; \
            int cd  = (c & 56) | ((c ^ row) & 7); \
            bf16x8 a = *(const bf16x8*)(lds + row * 1024 + cd * 16); \
            acc[0][m] = __builtin_amdgcn_mfma_f32_16x16x32_bf16(a, buf[j][0], acc[0][m], 0, 0, 0); \
            acc[1][m] = __builtin_amdgcn_mfma_f32_16x16x32_bf16(a, buf[j][1], acc[1][m], 0, 0, 0); } } }

#define CONS4_G23(buf, off) \
    { _Pragma("unroll") for (int j = 0; j < 4; ++j) { \
        int c = j * 4 + lh; \
        _Pragma("unroll") for (int m = 0; m < 2; ++m) { \
            int row = m * 16 + lr; \
            int sw  = (c & 8) | ((c ^ row) & 7); \
            bf16x8 a = *(const bf16x8*)(lds + row * 1024 + (off) + sw * 16); \
            acc[0][m] = __builtin_amdgcn_mfma_f32_16x16x32_bf16(a, buf[j][0], acc[0][m], 0, 0, 0); \
            acc[1][m] = __builtin_amdgcn_mfma_f32_16x16x32_bf16(a, buf[j][1], acc[1][m], 0, 0, 0); } } }

    // ---- GEMM1: [32x512] @ [512x128], 2-buffer x 4-kt register pipeline ----
    PREF4(bA, wp0, wp1, 0)
    PREF4(bB, wp0, wp1, 4)
    CONS4_G1(bA, 0)
    PREF4(bA, wp0, wp1, 8)
    CONS4_G1(bB, 4)
    PREF4(bB, wp0, wp1, 12)
    CONS4_G1(bA, 8)
    PREF4(b2, wq20, wq21, 0)          // GEMM2 weights issued a full phase early
    CONS4_G1(bB, 12)
    __syncthreads();   // all GEMM1 LDS reads done before h1 overwrites vff region

    // ---- bias + GELU -> h1 into +768 region ----
    {
        float bv0 = b11[n0], bv1 = b11[n1];
#pragma unroll
        for (int m = 0; m < 2; ++m)
#pragma unroll
            for (int i = 0; i < 4; ++i) {
                int row = m * 16 + lh * 4 + i;
                float v0 = geluf(acc[0][m][i] + bv0);
                float v1 = geluf(acc[1][m][i] + bv1);
                int ch0 = n0 >> 3, ch1 = n1 >> 3;
                int sw0 = (ch0 & 8) | ((ch0 ^ row) & 7);
                int sw1 = (ch1 & 8) | ((ch1 ^ row) & 7);
                *(unsigned short*)(lds + row * 1024 + 768 + sw0 * 16 + (n0 & 7) * 2) = bfr(v0);
                *(unsigned short*)(lds + row * 1024 + 768 + sw1 * 16 + (n1 & 7) * 2) = bfr(v1);
            }
    }
    PREF4(b3, wq30, wq31, 0)          // GEMM3 weights issued a full phase early
    __syncthreads();

    // ---- GEMM2: [32x128] @ [128x128] (weights already in b2) ----
#pragma unroll
    for (int j = 0; j < 2; ++j)
#pragma unroll
        for (int m = 0; m < 2; ++m) acc[j][m] = (f32x4){0.f, 0.f, 0.f, 0.f};
    CONS4_G23(b2, 768)
    // h2 region (+512) disjoint from h1 region (+768): no barrier before write
    {
        float bv0 = b12[n0], bv1 = b12[n1];
#pragma unroll
        for (int m = 0; m < 2; ++m)
#pragma unroll
            for (int i = 0; i < 4; ++i) {
                int row = m * 16 + lh * 4 + i;
                float v0 = geluf(acc[0][m][i] + bv0);
                float v1 = geluf(acc[1][m][i] + bv1);
                int ch0 = n0 >> 3, ch1 = n1 >> 3;
                int sw0 = (ch0 & 8) | ((ch0 ^ row) & 7);
                int sw1 = (ch1 & 8) | ((ch1 ^ row) & 7);
                *(unsigned short*)(lds + row * 1024 + 512 + sw0 * 16 + (n0 & 7) * 2) = bfr(v0);
                *(unsigned short*)(lds + row * 1024 + 512 + sw1 * 16 + (n1 & 7) * 2) = bfr(v1);
            }
    }
    __syncthreads();

    // ---- GEMM3: [32x128] @ [128x128] (weights already in b3) ----
#pragma unroll
    for (int j = 0; j < 2; ++j)
#pragma unroll
        for (int m = 0; m < 2; ++m) acc[j][m] = (f32x4){0.f, 0.f, 0.f, 0.f};
    CONS4_G23(b3, 512)

    // ---- epilogue: +b13, +h_E residual (LDS +256), nt-write x, BN partials ----
    {
        float bv0 = b13[n0], bv1 = b13[n1];
        float s0 = 0.f, q0 = 0.f, s1 = 0.f, q1 = 0.f;
#pragma unroll
        for (int m = 0; m < 2; ++m)
#pragma unroll
            for (int i = 0; i < 4; ++i) {
                int row = m * 16 + lh * 4 + i;
                size_t e = (size_t)(e0 + row);
                int c0 = 16 + (n0 >> 3);
                int c1 = 16 + (n1 >> 3);
                int d0 = (c0 & 56) | ((c0 ^ row) & 7);
                int d1 = (c1 & 56) | ((c1 ^ row) & 7);
                float he0 = bf2f(*(unsigned short*)(lds + row * 1024 + d0 * 16 + (n0 & 7) * 2));
                float he1 = bf2f(*(unsigned short*)(lds + row * 1024 + d1 * 16 + (n1 & 7) * 2));
                float x0 = acc[0][m][i] + bv0 + he0;
                float x1 = acc[1][m][i] + bv1 + he1;
                s0 += x0; q0 += x0 * x0;
                s1 += x1; q1 += x1 * x1;
                if (XBF16) {
                    __builtin_nontemporal_store(bfr(x0), xbf16 + e * HID + n0);
                    __builtin_nontemporal_store(bfr(x1), xbf16 + e * HID + n1);
                } else {
                    __builtin_nontemporal_store(x0, xf32 + e * HID + n0);
                    __builtin_nontemporal_store(x1, xf32 + e * HID + n1);
                }
            }
        s0 += __shfl_xor(s0, 16); s0 += __shfl_xor(s0, 32);
        q0 += __shfl_xor(q0, 16); q0 += __shfl_xor(q0, 32);
        s1 += __shfl_xor(s1, 16); s1 += __shfl_xor(s1, 32);
        q1 += __shfl_xor(q1, 16); q1 += __shfl_xor(q1, 32);
        if (lane < 16) {
            size_t base = (size_t)blockIdx.x * HID;
            psum[base + n0]   = s0;
            psum[base + n1]   = s1;
            psumsq[base + n0] = q0;
            psumsq[base + n1] = q1;
        }
    }
}

// ---------------- BN stats: reduce per-block partials -> scale/shift ----------------
__global__ void bn_stats_kernel(const float* __restrict__ psum, const float* __restrict__ psumsq,
                                const float* __restrict__ gamma, const float* __restrict__ beta,
                                float* __restrict__ params, int nblk, float invE) {
    int c = blockIdx.x;   // channel 0..127
    float s = 0.f, q = 0.f;
    for (int i = threadIdx.x; i < nblk; i += 256) {
        s += psum[(size_t)i * 128 + c];
        q += psumsq[(size_t)i * 128 + c];
    }
#pragma unroll
    for (int o = 1; o < 64; o <<= 1) { s += __shfl_xor(s, o); q += __shfl_xor(q, o); }
    __shared__ float as[4], aq[4];
    int w = threadIdx.x >> 6;
    if ((threadIdx.x & 63) == 0) { as[w] = s; aq[w] = q; }
    __syncthreads();
    if (threadIdx.x == 0) {
        float S  = as[0] + as[1] + as[2] + as[3];
        float Q  = aq[0] + aq[1] + aq[2] + aq[3];
        float mean = S * invE;
        float var  = Q * invE - mean * mean;
        float sc   = gamma[c] * rsqrtf(var + 1e-5f);
        params[c]       = sc;
        params[128 + c] = beta[c] - mean * sc;
    }
}

// ---------------- BN apply ----------------
__global__ void bn_apply_bf16(const unsigned short* __restrict__ x, float* __restrict__ out,
                              const float* __restrict__ params, int total8) {
    __shared__ float sc[128], sh[128];
    if (threadIdx.x < 128) { sc[threadIdx.x] = params[threadIdx.x]; sh[threadIdx.x] = params[128 + threadIdx.x]; }
    __syncthreads();
    int stride = gridDim.x * blockDim.x;
    for (int i = blockIdx.x * blockDim.x + threadIdx.x; i < total8; i += stride) {
        size_t base = (size_t)i * 8;
        u16x8 v = __builtin_nontemporal_load((const u16x8*)(x + base));
        int c0 = (int)(base & 127);
        f32x4 o0, o1;
#pragma unroll
        for (int e = 0; e < 4; ++e) o0[e] = bf2f(v[e]) * sc[c0 + e] + sh[c0 + e];
#pragma unroll
        for (int e = 0; e < 4; ++e) o1[e] = bf2f(v[4 + e]) * sc[c0 + 4 + e] + sh[c0 + 4 + e];
        __builtin_nontemporal_store(o0, (f32x4*)(out + base));
        __builtin_nontemporal_store(o1, (f32x4*)(out + base + 4));
    }
}

__global__ void bn_apply_f32(float* __restrict__ x, const float* __restrict__ params, int total4) {
    __shared__ float sc[128], sh[128];
    if (threadIdx.x < 128) { sc[threadIdx.x] = params[threadIdx.x]; sh[threadIdx.x] = params[128 + threadIdx.x]; }
    __syncthreads();
    int stride = gridDim.x * blockDim.x;
    for (int i = blockIdx.x * blockDim.x + threadIdx.x; i < total4; i += stride) {
        size_t base = (size_t)i * 4;
        f32x4 v = *(f32x4*)(x + base);
        int c0 = (int)(base & 127);
#pragma unroll
        for (int e = 0; e < 4; ++e) v[e] = v[e] * sc[c0 + e] + sh[c0 + e];
        *(f32x4*)(x + base) = v;
    }
}

extern "C" void kernel_launch(void* const* d_in, const int* in_sizes, int n_in,
                              void* d_out, int out_size, void* d_ws, size_t ws_size,
                              hipStream_t stream) {
    const float* hV    = (const float*)d_in[0];
    const float* hE    = (const float*)d_in[1];
    const int*   eidx  = (const int*)d_in[2];
    const float* vff   = (const float*)d_in[4];
    const float* W11   = (const float*)d_in[5];
    const float* b11   = (const float*)d_in[6];
    const float* W12   = (const float*)d_in[7];
    const float* b12   = (const float*)d_in[8];
    const float* W13   = (const float*)d_in[9];
    const float* b13   = (const float*)d_in[10];
    const float* gamma = (const float*)d_in[11];
    const float* beta  = (const float*)d_in[12];

    const int E    = in_sizes[1] / HID;
    const int nblk = E / BM;   // 400000/32 = 12500

    float* psum   = (float*)d_ws;
    float* psumsq = psum + (size_t)nblk * HID;
    float* params = psumsq + (size_t)nblk * HID;
    unsigned short* w11t = (unsigned short*)(params + 256);
    unsigned short* w12t = w11t + 512 * 128;
    unsigned short* w13t = w12t + 128 * 128;
    size_t xoff = ((size_t)((char*)(w13t + 128 * 128) - (char*)d_ws) + 15) & ~(size_t)15;
    unsigned short* xbf = (unsigned short*)((char*)d_ws + xoff);
    const bool useBf = ws_size >= xoff + (size_t)E * HID * 2;

    prep_weights<<<384, 256, 0, stream>>>(W11, W12, W13, w11t, w12t, w13t);

    if (useBf)
        edge_mlp_kernel<1><<<nblk, 256, 0, stream>>>(hV, hE, eidx, vff, w11t, w12t, w13t,
                                                     b11, b12, b13, psum, psumsq,
                                                     (float*)d_out, xbf, E);
    else
        edge_mlp_kernel<0><<<nblk, 256, 0, stream>>>(hV, hE, eidx, vff, w11t, w12t, w13t,
                                                     b11, b12, b13, psum, psumsq,
                                                     (float*)d_out, xbf, E);

    bn_stats_kernel<<<128, 256, 0, stream>>>(psum, psumsq, gamma, beta, params, nblk,
                                             1.0f / (float)E);

    if (useBf)
        bn_apply_bf16<<<2048, 256, 0, stream>>>(xbf, (float*)d_out, params, E * HID / 8);
    else
        bn_apply_f32<<<2048, 256, 0, stream>>>((float*)d_out, params, E * HID / 4);
}

// Round 5
// 435.773 us; speedup vs baseline: 2.4211x; 1.1519x over previous
//
#include <hip/hip_runtime.h>
#include <hip/hip_bf16.h>
#include <math.h>

typedef __attribute__((ext_vector_type(8))) short  bf16x8;
typedef __attribute__((ext_vector_type(4))) float  f32x4;
typedef __attribute__((ext_vector_type(8))) unsigned short u16x8;

#define HID  128
#define BM   32
#define LROW 1280   // edge-kernel LDS row stride (bytes)

__device__ __forceinline__ unsigned short f2bf(float f) {
    union { float f; unsigned u; } v; v.f = f;
    unsigned u = v.u;
    return (unsigned short)((u + 0x7fffu + ((u >> 16) & 1u)) >> 16);
}
__device__ __forceinline__ unsigned pkbf(float a, float b) {
    __hip_bfloat162 h2 = __float22bfloat162_rn(float2{a, b});
    union { __hip_bfloat162 h; unsigned u; } u; u.h = h2; return u.u;
}
__device__ __forceinline__ unsigned short bfr(float f) {
    __hip_bfloat16 h = __float2bfloat16(f);
    union { __hip_bfloat16 h; unsigned short s; } u; u.h = h; return u.s;
}
__device__ __forceinline__ float bf2f(unsigned short h) {
    union { unsigned u; float f; } v; v.u = ((unsigned)h) << 16;
    return v.f;
}
// tanh-form GELU: max |diff vs exact| ~3e-4
__device__ __forceinline__ float geluf(float x) {
    float x2 = x * x;
    float u  = __builtin_fmaf(0.044715f * x2, x, x);
    float e  = __builtin_amdgcn_exp2f(u * 2.30220795f);
    return x * e * __builtin_amdgcn_rcpf(e + 1.0f);
}

// ---------------- weight prep ----------------
// wa  = W11 rows   0..127 (hV-src part),  transposed bf16 [128n][128k]
// wc  = W11 rows 256..383 (hV-dst part),  transposed bf16 [128n][128k]
// wbd = W11 rows 128..255 (hE) ++ 384..511 (vff), transposed bf16 [128n][256k]
__global__ void prep_weights(const float* __restrict__ W11, const float* __restrict__ W12,
                             const float* __restrict__ W13,
                             unsigned short* __restrict__ wa, unsigned short* __restrict__ wc,
                             unsigned short* __restrict__ wbd,
                             unsigned short* __restrict__ w12t, unsigned short* __restrict__ w13t) {
    int idx = blockIdx.x * 256 + threadIdx.x;
    if (idx < 16384) {
        int k = idx >> 7, n = idx & 127;
        wa[n * 128 + k] = f2bf(W11[k * 128 + n]);
    } else if (idx < 32768) {
        int j = idx - 16384; int k = j >> 7, n = j & 127;
        wc[n * 128 + k] = f2bf(W11[(256 + k) * 128 + n]);
    } else if (idx < 65536) {
        int j = idx - 32768; int k = j >> 7, n = j & 127;
        int row = (k < 128) ? (128 + k) : (256 + k);   // 256+k == 384+(k-128)
        wbd[n * 256 + k] = f2bf(W11[row * 128 + n]);
    } else if (idx < 81920) {
        int j = idx - 65536; int k = j >> 7, n = j & 127;
        w12t[n * 128 + k] = f2bf(W12[k * 128 + n]);
    } else if (idx < 98304) {
        int j = idx - 81920; int k = j >> 7, n = j & 127;
        w13t[n * 128 + k] = f2bf(W13[k * 128 + n]);
    }
}

// ---------------- P tables: P1 = hV@Wa + b11, P2 = hV@Wc (bf16) ----------------
__global__ __launch_bounds__(256, 4) void p_kernel(
    const float* __restrict__ hV,
    const unsigned short* __restrict__ wa, const unsigned short* __restrict__ wc,
    const float* __restrict__ b11,
    unsigned short* __restrict__ P1, unsigned short* __restrict__ P2, int nV)
{
    __shared__ __align__(16) char lds[BM * 512];
    const int tid = threadIdx.x, lane = tid & 63, wid = tid >> 6;
    const int lr = lane & 15, lh = lane >> 4;
    const int v0 = blockIdx.x * BM;

    {
        int r = tid >> 3, sub = tid & 7;
        int v = v0 + r; if (v >= nV) v = nV - 1;
        const float* sp = hV + (size_t)v * HID + sub * 16;
        f32x4 a0 = __builtin_nontemporal_load((const f32x4*)sp);
        f32x4 a1 = __builtin_nontemporal_load((const f32x4*)sp + 1);
        f32x4 a2 = __builtin_nontemporal_load((const f32x4*)sp + 2);
        f32x4 a3 = __builtin_nontemporal_load((const f32x4*)sp + 3);
        union { u16x8 s; unsigned u[4]; } pA, pB;
        pA.u[0] = pkbf(a0[0], a0[1]); pA.u[1] = pkbf(a0[2], a0[3]);
        pA.u[2] = pkbf(a1[0], a1[1]); pA.u[3] = pkbf(a1[2], a1[3]);
        pB.u[0] = pkbf(a2[0], a2[1]); pB.u[1] = pkbf(a2[2], a2[3]);
        pB.u[2] = pkbf(a3[0], a3[1]); pB.u[3] = pkbf(a3[2], a3[3]);
        int c0 = sub * 2, c1 = c0 + 1;
        int s0 = (c0 & 8) | ((c0 ^ r) & 7), s1 = (c1 & 8) | ((c1 ^ r) & 7);
        *(u16x8*)(lds + r * 512 + s0 * 16) = pA.s;
        *(u16x8*)(lds + r * 512 + s1 * 16) = pB.s;
    }
    __syncthreads();

    const int n0 = wid * 32 + lr, n1 = n0 + 16;
    f32x4 acc1[2][2], acc2[2][2];
#pragma unroll
    for (int j = 0; j < 2; ++j)
#pragma unroll
        for (int m = 0; m < 2; ++m) { acc1[j][m] = (f32x4){0,0,0,0}; acc2[j][m] = (f32x4){0,0,0,0}; }

    const unsigned short* a0p = wa + n0 * 128 + lh * 8;
    const unsigned short* a1p = wa + n1 * 128 + lh * 8;
    const unsigned short* c0p = wc + n0 * 128 + lh * 8;
    const unsigned short* c1p = wc + n1 * 128 + lh * 8;
#pragma unroll
    for (int kt = 0; kt < 4; ++kt) {
        bf16x8 ba0 = *(const bf16x8*)(a0p + kt * 32);
        bf16x8 ba1 = *(const bf16x8*)(a1p + kt * 32);
        bf16x8 bc0 = *(const bf16x8*)(c0p + kt * 32);
        bf16x8 bc1 = *(const bf16x8*)(c1p + kt * 32);
        int c = kt * 4 + lh;
#pragma unroll
        for (int m = 0; m < 2; ++m) {
            int row = m * 16 + lr;
            int sw  = (c & 8) | ((c ^ row) & 7);
            bf16x8 a = *(const bf16x8*)(lds + row * 512 + sw * 16);
            acc1[0][m] = __builtin_amdgcn_mfma_f32_16x16x32_bf16(a, ba0, acc1[0][m], 0, 0, 0);
            acc1[1][m] = __builtin_amdgcn_mfma_f32_16x16x32_bf16(a, ba1, acc1[1][m], 0, 0, 0);
            acc2[0][m] = __builtin_amdgcn_mfma_f32_16x16x32_bf16(a, bc0, acc2[0][m], 0, 0, 0);
            acc2[1][m] = __builtin_amdgcn_mfma_f32_16x16x32_bf16(a, bc1, acc2[1][m], 0, 0, 0);
        }
    }
    float bv0 = b11[n0], bv1 = b11[n1];
#pragma unroll
    for (int m = 0; m < 2; ++m)
#pragma unroll
        for (int i = 0; i < 4; ++i) {
            int row = m * 16 + lh * 4 + i;
            int v = v0 + row;
            if (v < nV) {
                size_t b = (size_t)v * HID;
                P1[b + n0] = bfr(acc1[0][m][i] + bv0);
                P1[b + n1] = bfr(acc1[1][m][i] + bv1);
                P2[b + n0] = bfr(acc2[0][m][i]);
                P2[b + n1] = bfr(acc2[1][m][i]);
            }
        }
}

// ---------------- fused edge MLP + residual + BN partials ----------------
// LDS row (1280B): [hE 0 | vff/h2 256 | h1/x 512 | P1 768 | P2 1024], chunks
// XOR-swizzled within each 16-chunk region: slot = (c&8)|((c^row)&7).
// 40KB LDS -> 4 blocks/CU at __launch_bounds__(256,4) (128 VGPR budget).
template <int XBF16>
__global__ __launch_bounds__(256, 4) void edge_mlp_kernel(
    const float* __restrict__ hE, const int* __restrict__ eidx,
    const float* __restrict__ vff,
    const unsigned short* __restrict__ P1, const unsigned short* __restrict__ P2,
    const unsigned short* __restrict__ wbd, const unsigned short* __restrict__ w12t,
    const unsigned short* __restrict__ w13t,
    const float* __restrict__ b12, const float* __restrict__ b13,
    float* __restrict__ psum, float* __restrict__ psumsq,
    float* __restrict__ xf32, unsigned short* __restrict__ xbf16, int E)
{
    __shared__ __align__(16) char lds[BM * LROW];
    const int tid = threadIdx.x, lane = tid & 63, wid = tid >> 6;
    const int lr = lane & 15, lh = lane >> 4;
    const int e0 = blockIdx.x * BM;
    const bool idx64 = ((eidx[1] | eidx[3] | eidx[5] | eidx[7]) == 0);
    const int n0 = wid * 32 + lr, n1 = n0 + 16;

    // ---- staging: P gathers (bf16, direct copy) + hE/vff stream (f32->bf16) ----
    {
        int r = tid >> 3, sub = tid & 7;
        int e = e0 + r;
        int sIdx = idx64 ? eidx[2 * e]       : eidx[e];
        int dIdx = idx64 ? eidx[2 * (E + e)] : eidx[E + e];
        const unsigned short* pt = (sub < 4) ? (P1 + (size_t)sIdx * HID)
                                             : (P2 + (size_t)dIdx * HID);
        int csub = (sub & 3) * 4;
        u16x8 g0 = *(const u16x8*)(pt + (csub + 0) * 8);
        u16x8 g1 = *(const u16x8*)(pt + (csub + 1) * 8);
        u16x8 g2 = *(const u16x8*)(pt + (csub + 2) * 8);
        u16x8 g3 = *(const u16x8*)(pt + (csub + 3) * 8);

        const float* spE = hE  + (size_t)e * HID + sub * 16;
        const float* spV = vff + (size_t)e * HID + sub * 16;
        f32x4 h0 = __builtin_nontemporal_load((const f32x4*)spE);
        f32x4 h1 = __builtin_nontemporal_load((const f32x4*)spE + 1);
        f32x4 h2 = __builtin_nontemporal_load((const f32x4*)spE + 2);
        f32x4 h3 = __builtin_nontemporal_load((const f32x4*)spE + 3);
        f32x4 v0 = __builtin_nontemporal_load((const f32x4*)spV);
        f32x4 v1 = __builtin_nontemporal_load((const f32x4*)spV + 1);
        f32x4 v2 = __builtin_nontemporal_load((const f32x4*)spV + 2);
        f32x4 v3 = __builtin_nontemporal_load((const f32x4*)spV + 3);

        int poff = (sub < 4) ? 768 : 1024;
        int pc0 = csub, pc1 = csub + 1, pc2 = csub + 2, pc3 = csub + 3;
        *(u16x8*)(lds + r * LROW + poff + (((pc0 & 8) | ((pc0 ^ r) & 7))) * 16) = g0;
        *(u16x8*)(lds + r * LROW + poff + (((pc1 & 8) | ((pc1 ^ r) & 7))) * 16) = g1;
        *(u16x8*)(lds + r * LROW + poff + (((pc2 & 8) | ((pc2 ^ r) & 7))) * 16) = g2;
        *(u16x8*)(lds + r * LROW + poff + (((pc3 & 8) | ((pc3 ^ r) & 7))) * 16) = g3;

        union { u16x8 s; unsigned u[4]; } cE0, cE1, cV0, cV1;
        cE0.u[0] = pkbf(h0[0], h0[1]); cE0.u[1] = pkbf(h0[2], h0[3]);
        cE0.u[2] = pkbf(h1[0], h1[1]); cE0.u[3] = pkbf(h1[2], h1[3]);
        cE1.u[0] = pkbf(h2[0], h2[1]); cE1.u[1] = pkbf(h2[2], h2[3]);
        cE1.u[2] = pkbf(h3[0], h3[1]); cE1.u[3] = pkbf(h3[2], h3[3]);
        cV0.u[0] = pkbf(v0[0], v0[1]); cV0.u[1] = pkbf(v0[2], v0[3]);
        cV0.u[2] = pkbf(v1[0], v1[1]); cV0.u[3] = pkbf(v1[2], v1[3]);
        cV1.u[0] = pkbf(v2[0], v2[1]); cV1.u[1] = pkbf(v2[2], v2[3]);
        cV1.u[2] = pkbf(v3[0], v3[1]); cV1.u[3] = pkbf(v3[2], v3[3]);
        int c0 = sub * 2, c1 = c0 + 1;
        int s0 = (c0 & 8) | ((c0 ^ r) & 7), s1 = (c1 & 8) | ((c1 ^ r) & 7);
        *(u16x8*)(lds + r * LROW +   0 + s0 * 16) = cE0.s;
        *(u16x8*)(lds + r * LROW +   0 + s1 * 16) = cE1.s;
        *(u16x8*)(lds + r * LROW + 256 + s0 * 16) = cV0.s;
        *(u16x8*)(lds + r * LROW + 256 + s1 * 16) = cV1.s;
    }
    __syncthreads();

    f32x4 acc[2][2];
#pragma unroll
    for (int j = 0; j < 2; ++j)
#pragma unroll
        for (int m = 0; m < 2; ++m) acc[j][m] = (f32x4){0, 0, 0, 0};

    const unsigned short* w0p = wbd  + n0 * 256 + lh * 8;
    const unsigned short* w1p = wbd  + n1 * 256 + lh * 8;
    const unsigned short* q20 = w12t + n0 * 128 + lh * 8;
    const unsigned short* q21 = w12t + n1 * 128 + lh * 8;
    const unsigned short* q30 = w13t + n0 * 128 + lh * 8;
    const unsigned short* q31 = w13t + n1 * 128 + lh * 8;

    bf16x8 bA[4][2], bB[4][2], b2[4][2], b3[4][2];

#define PREF4(buf, p0, p1, base) \
    { _Pragma("unroll") for (int j = 0; j < 4; ++j) { \
        buf[j][0] = *(const bf16x8*)((p0) + ((base) + j) * 32); \
        buf[j][1] = *(const bf16x8*)((p1) + ((base) + j) * 32); } }

#define CONS4(buf, off) \
    { _Pragma("unroll") for (int j = 0; j < 4; ++j) { \
        int c = j * 4 + lh; \
        _Pragma("unroll") for (int m = 0; m < 2; ++m) { \
            int row = m * 16 + lr; \
            int sw  = (c & 8) | ((c ^ row) & 7); \
            bf16x8 a = *(const bf16x8*)(lds + row * LROW + (off) + sw * 16); \
            acc[0][m] = __builtin_amdgcn_mfma_f32_16x16x32_bf16(a, buf[j][0], acc[0][m], 0, 0, 0); \
            acc[1][m] = __builtin_amdgcn_mfma_f32_16x16x32_bf16(a, buf[j][1], acc[1][m], 0, 0, 0); } } }

    // ---- GEMM1: [32x256] @ [256x128] ----
    PREF4(bA, w0p, w1p, 0)
    PREF4(bB, w0p, w1p, 4)
    CONS4(bA, 0)                 // hE half
    PREF4(b2, q20, q21, 0)
    CONS4(bB, 256)               // vff half

    // ---- GELU1: + P1 + P2 (b11 folded into P1), h1 -> region 512 ----
#pragma unroll
    for (int m = 0; m < 2; ++m)
#pragma unroll
        for (int i = 0; i < 4; ++i) {
            int row = m * 16 + lh * 4 + i;
            int ch0 = n0 >> 3, ch1 = n1 >> 3;
            int s0 = (ch0 & 8) | ((ch0 ^ row) & 7);
            int s1 = (ch1 & 8) | ((ch1 ^ row) & 7);
            float p10 = bf2f(*(const unsigned short*)(lds + row * LROW +  768 + s0 * 16 + (n0 & 7) * 2));
            float p11 = bf2f(*(const unsigned short*)(lds + row * LROW +  768 + s1 * 16 + (n1 & 7) * 2));
            float p20 = bf2f(*(const unsigned short*)(lds + row * LROW + 1024 + s0 * 16 + (n0 & 7) * 2));
            float p21 = bf2f(*(const unsigned short*)(lds + row * LROW + 1024 + s1 * 16 + (n1 & 7) * 2));
            float v0 = geluf(acc[0][m][i] + p10 + p20);
            float v1 = geluf(acc[1][m][i] + p11 + p21);
            *(unsigned short*)(lds + row * LROW + 512 + s0 * 16 + (n0 & 7) * 2) = bfr(v0);
            *(unsigned short*)(lds + row * LROW + 512 + s1 * 16 + (n1 & 7) * 2) = bfr(v1);
        }
    PREF4(b3, q30, q31, 0)
    __syncthreads();

    // ---- GEMM2 ----
#pragma unroll
    for (int j = 0; j < 2; ++j)
#pragma unroll
        for (int m = 0; m < 2; ++m) acc[j][m] = (f32x4){0, 0, 0, 0};
    CONS4(b2, 512)
    {
        float bv0 = b12[n0], bv1 = b12[n1];
#pragma unroll
        for (int m = 0; m < 2; ++m)
#pragma unroll
            for (int i = 0; i < 4; ++i) {
                int row = m * 16 + lh * 4 + i;
                int ch0 = n0 >> 3, ch1 = n1 >> 3;
                int s0 = (ch0 & 8) | ((ch0 ^ row) & 7);
                int s1 = (ch1 & 8) | ((ch1 ^ row) & 7);
                float v0 = geluf(acc[0][m][i] + bv0);
                float v1 = geluf(acc[1][m][i] + bv1);
                *(unsigned short*)(lds + row * LROW + 256 + s0 * 16 + (n0 & 7) * 2) = bfr(v0);
                *(unsigned short*)(lds + row * LROW + 256 + s1 * 16 + (n1 & 7) * 2) = bfr(v1);
            }
    }
    __syncthreads();

    // ---- GEMM3 ----
#pragma unroll
    for (int j = 0; j < 2; ++j)
#pragma unroll
        for (int m = 0; m < 2; ++m) acc[j][m] = (f32x4){0, 0, 0, 0};
    CONS4(b3, 256)

    // ---- epilogue: +b13 +hE residual, BN partials, x -> region 512 ----
    {
        float bv0 = b13[n0], bv1 = b13[n1];
        float s0a = 0.f, q0a = 0.f, s1a = 0.f, q1a = 0.f;
#pragma unroll
        for (int m = 0; m < 2; ++m)
#pragma unroll
            for (int i = 0; i < 4; ++i) {
                int row = m * 16 + lh * 4 + i;
                int ch0 = n0 >> 3, ch1 = n1 >> 3;
                int s0 = (ch0 & 8) | ((ch0 ^ row) & 7);
                int s1 = (ch1 & 8) | ((ch1 ^ row) & 7);
                float he0 = bf2f(*(const unsigned short*)(lds + row * LROW + s0 * 16 + (n0 & 7) * 2));
                float he1 = bf2f(*(const unsigned short*)(lds + row * LROW + s1 * 16 + (n1 & 7) * 2));
                float x0 = acc[0][m][i] + bv0 + he0;
                float x1 = acc[1][m][i] + bv1 + he1;
                s0a += x0; q0a += x0 * x0;
                s1a += x1; q1a += x1 * x1;
                *(unsigned short*)(lds + row * LROW + 512 + s0 * 16 + (n0 & 7) * 2) = bfr(x0);
                *(unsigned short*)(lds + row * LROW + 512 + s1 * 16 + (n1 & 7) * 2) = bfr(x1);
            }
        s0a += __shfl_xor(s0a, 16); s0a += __shfl_xor(s0a, 32);
        q0a += __shfl_xor(q0a, 16); q0a += __shfl_xor(q0a, 32);
        s1a += __shfl_xor(s1a, 16); s1a += __shfl_xor(s1a, 32);
        q1a += __shfl_xor(q1a, 16); q1a += __shfl_xor(q1a, 32);
        if (lane < 16) {
            size_t base = (size_t)blockIdx.x * HID;
            psum[base + n0]   = s0a;
            psum[base + n1]   = s1a;
            psumsq[base + n0] = q0a;
            psumsq[base + n1] = q1a;
        }
    }
    __syncthreads();

    // ---- coalesced x write (16B/lane) ----
    {
        int r = tid >> 3, sub = tid & 7;
        int c0 = sub * 2, c1 = c0 + 1;
        int s0 = (c0 & 8) | ((c0 ^ r) & 7), s1 = (c1 & 8) | ((c1 ^ r) & 7);
        u16x8 X0 = *(const u16x8*)(lds + r * LROW + 512 + s0 * 16);
        u16x8 X1 = *(const u16x8*)(lds + r * LROW + 512 + s1 * 16);
        size_t base = (size_t)(e0 + r) * HID;
        if (XBF16) {
            __builtin_nontemporal_store(X0, (u16x8*)(xbf16 + base + c0 * 8));
            __builtin_nontemporal_store(X1, (u16x8*)(xbf16 + base + c1 * 8));
        } else {
            f32x4 o0, o1, o2, o3;
#pragma unroll
            for (int e = 0; e < 4; ++e) {
                o0[e] = bf2f(X0[e]); o1[e] = bf2f(X0[4 + e]);
                o2[e] = bf2f(X1[e]); o3[e] = bf2f(X1[4 + e]);
            }
            __builtin_nontemporal_store(o0, (f32x4*)(xf32 + base + c0 * 8));
            __builtin_nontemporal_store(o1, (f32x4*)(xf32 + base + c0 * 8 + 4));
            __builtin_nontemporal_store(o2, (f32x4*)(xf32 + base + c1 * 8));
            __builtin_nontemporal_store(o3, (f32x4*)(xf32 + base + c1 * 8 + 4));
        }
    }
}

// ---------------- BN stats ----------------
__global__ void bn_stats_kernel(const float* __restrict__ psum, const float* __restrict__ psumsq,
                                const float* __restrict__ gamma, const float* __restrict__ beta,
                                float* __restrict__ params, int nblk, float invE) {
    int c = blockIdx.x;
    float s = 0.f, q = 0.f;
    for (int i = threadIdx.x; i < nblk; i += 256) {
        s += psum[(size_t)i * 128 + c];
        q += psumsq[(size_t)i * 128 + c];
    }
#pragma unroll
    for (int o = 1; o < 64; o <<= 1) { s += __shfl_xor(s, o); q += __shfl_xor(q, o); }
    __shared__ float as[4], aq[4];
    int w = threadIdx.x >> 6;
    if ((threadIdx.x & 63) == 0) { as[w] = s; aq[w] = q; }
    __syncthreads();
    if (threadIdx.x == 0) {
        float S = as[0] + as[1] + as[2] + as[3];
        float Q = aq[0] + aq[1] + aq[2] + aq[3];
        float mean = S * invE;
        float var  = Q * invE - mean * mean;
        float sc   = gamma[c] * rsqrtf(var + 1e-5f);
        params[c]       = sc;
        params[128 + c] = beta[c] - mean * sc;
    }
}

// ---------------- BN apply ----------------
__global__ void bn_apply_bf16(const unsigned short* __restrict__ x, float* __restrict__ out,
                              const float* __restrict__ params, int total8) {
    __shared__ float sc[128], sh[128];
    if (threadIdx.x < 128) { sc[threadIdx.x] = params[threadIdx.x]; sh[threadIdx.x] = params[128 + threadIdx.x]; }
    __syncthreads();
    int stride = gridDim.x * blockDim.x;
    for (int i = blockIdx.x * blockDim.x + threadIdx.x; i < total8; i += stride) {
        size_t base = (size_t)i * 8;
        u16x8 v = __builtin_nontemporal_load((const u16x8*)(x + base));
        int c0 = (int)(base & 127);
        f32x4 o0, o1;
#pragma unroll
        for (int e = 0; e < 4; ++e) o0[e] = bf2f(v[e]) * sc[c0 + e] + sh[c0 + e];
#pragma unroll
        for (int e = 0; e < 4; ++e) o1[e] = bf2f(v[4 + e]) * sc[c0 + 4 + e] + sh[c0 + 4 + e];
        __builtin_nontemporal_store(o0, (f32x4*)(out + base));
        __builtin_nontemporal_store(o1, (f32x4*)(out + base + 4));
    }
}

__global__ void bn_apply_f32(float* __restrict__ x, const float* __restrict__ params, int total4) {
    __shared__ float sc[128], sh[128];
    if (threadIdx.x < 128) { sc[threadIdx.x] = params[threadIdx.x]; sh[threadIdx.x] = params[128 + threadIdx.x]; }
    __syncthreads();
    int stride = gridDim.x * blockDim.x;
    for (int i = blockIdx.x * blockDim.x + threadIdx.x; i < total4; i += stride) {
        size_t base = (size_t)i * 4;
        f32x4 v = *(f32x4*)(x + base);
        int c0 = (int)(base & 127);
#pragma unroll
        for (int e = 0; e < 4; ++e) v[e] = v[e] * sc[c0 + e] + sh[c0 + e];
        *(f32x4*)(x + base) = v;
    }
}

extern "C" void kernel_launch(void* const* d_in, const int* in_sizes, int n_in,
                              void* d_out, int out_size, void* d_ws, size_t ws_size,
                              hipStream_t stream) {
    const float* hV    = (const float*)d_in[0];
    const float* hE    = (const float*)d_in[1];
    const int*   eidx  = (const int*)d_in[2];
    const float* vff   = (const float*)d_in[4];
    const float* W11   = (const float*)d_in[5];
    const float* b11   = (const float*)d_in[6];
    const float* W12   = (const float*)d_in[7];
    const float* b12   = (const float*)d_in[8];
    const float* W13   = (const float*)d_in[9];
    const float* b13   = (const float*)d_in[10];
    const float* gamma = (const float*)d_in[11];
    const float* beta  = (const float*)d_in[12];

    const int nV    = in_sizes[0] / HID;          // 50000
    const int E     = in_sizes[1] / HID;          // 400000
    const int nblk  = E / BM;                     // 12500
    const int nblkV = (nV + BM - 1) / BM;         // 1563
    const int nVp   = nblkV * BM;                 // padded node rows

    float* params = (float*)d_ws;                           // 256 f32
    unsigned short* wa   = (unsigned short*)(params + 256);
    unsigned short* wc   = wa   + 16384;
    unsigned short* wbd  = wc   + 16384;
    unsigned short* w12t = wbd  + 32768;
    unsigned short* w13t = w12t + 16384;
    float* psum   = (float*)(w13t + 16384);
    float* psumsq = psum + (size_t)nblk * HID;
    unsigned short* P1 = (unsigned short*)(psumsq + (size_t)nblk * HID);
    unsigned short* P2 = P1 + (size_t)nVp * HID;
    unsigned short* xbf = P2 + (size_t)nVp * HID;
    const size_t fixed = (size_t)((char*)xbf - (char*)d_ws);
    const bool useBf = ws_size >= fixed + (size_t)E * HID * 2;

    prep_weights<<<384, 256, 0, stream>>>(W11, W12, W13, wa, wc, wbd, w12t, w13t);
    p_kernel<<<nblkV, 256, 0, stream>>>(hV, wa, wc, b11, P1, P2, nV);

    if (useBf)
        edge_mlp_kernel<1><<<nblk, 256, 0, stream>>>(hE, eidx, vff, P1, P2, wbd, w12t, w13t,
                                                     b12, b13, psum, psumsq,
                                                     (float*)d_out, xbf, E);
    else
        edge_mlp_kernel<0><<<nblk, 256, 0, stream>>>(hE, eidx, vff, P1, P2, wbd, w12t, w13t,
                                                     b12, b13, psum, psumsq,
                                                     (float*)d_out, xbf, E);

    bn_stats_kernel<<<128, 256, 0, stream>>>(psum, psumsq, gamma, beta, params, nblk,
                                             1.0f / (float)E);

    if (useBf)
        bn_apply_bf16<<<2048, 256, 0, stream>>>(xbf, (float*)d_out, params, E * HID / 8);
    else
        bn_apply_f32<<<2048, 256, 0, stream>>>((float*)d_out, params, E * HID / 4);
}